// Round 8
// baseline (4802.827 us; speedup 1.0000x reference)
//
#include <hip/hip_runtime.h>
#include <hip/hip_bf16.h>
#include <stdint.h>

#define N_RES 4096
#define BATCH 8
#define T_STEPS 256
#define VOCAB 32000
#define R_OUT 512
#define NNZ 131072
#define NNZ_CAP 163840
#define TEAMS 8             // one per batch
#define SLICES 8            // WGs per team
#define ROWS_PS 512         // rows per WG
#define NWG (TEAMS*SLICES)  // 64
#define CSR_CAP 18432       // entries per slice in LDS

typedef _Float16 v8h __attribute__((ext_vector_type(8)));
typedef float v4f __attribute__((ext_vector_type(4)));

static __device__ __forceinline__ unsigned short f2h(float f) {
    _Float16 h = (_Float16)f;
    unsigned short u;
    __builtin_memcpy(&u, &h, 2);
    return u;
}
static __device__ __forceinline__ float h2f(unsigned short u) {
    _Float16 h;
    __builtin_memcpy(&h, &u, 2);
    return (float)h;
}

// ---------------- init / CSR build ----------------

__global__ __launch_bounds__(256) void k_hist(const int* __restrict__ rows,
                                              int* __restrict__ cnt) {
    int i = blockIdx.x * 256 + threadIdx.x;
    if (i < NNZ) atomicAdd(&cnt[rows[i]], 1);
}

// padded scan: each row's span rounded up to multiple of 4
__global__ __launch_bounds__(1024) void k_scan(const int* __restrict__ cnt,
                                               int* __restrict__ row_ptr,
                                               int* __restrict__ cursor) {
    __shared__ int sm[1024];
    int t = threadIdx.x;
    int base = t * 4;
    int c0 = (cnt[base] + 3) & ~3;
    int c1 = (cnt[base + 1] + 3) & ~3;
    int c2 = (cnt[base + 2] + 3) & ~3;
    int c3 = (cnt[base + 3] + 3) & ~3;
    int s = c0 + c1 + c2 + c3;
    sm[t] = s;
    __syncthreads();
    for (int off = 1; off < 1024; off <<= 1) {
        int v = (t >= off) ? sm[t - off] : 0;
        __syncthreads();
        sm[t] += v;
        __syncthreads();
    }
    int run = sm[t] - s;
    row_ptr[base] = run;     cursor[base] = run;     run += c0;
    row_ptr[base + 1] = run; cursor[base + 1] = run; run += c1;
    row_ptr[base + 2] = run; cursor[base + 2] = run; run += c2;
    row_ptr[base + 3] = run; cursor[base + 3] = run; run += c3;
    if (t == 1023) row_ptr[4096] = run;
}

// packed CSR entry: plane BYTE offset (col*4) in hi16, f16 value in lo16.
__global__ __launch_bounds__(256) void k_fill(const int* __restrict__ rows,
                                              const int* __restrict__ cols,
                                              const float* __restrict__ vals,
                                              int* __restrict__ cursor,
                                              unsigned* __restrict__ csr) {
    int i = blockIdx.x * 256 + threadIdx.x;
    if (i < NNZ) {
        int r = rows[i];
        unsigned off = (unsigned)(cols[i] << 2);
        int p = atomicAdd(&cursor[r], 1);
        csr[p] = (off << 16) | (unsigned)f2h(vals[i]);
    }
}

// ---------------- f32 -> f16 convert (for B_w, A_w) ----------------

__global__ __launch_bounds__(256) void k_cvt(const float* __restrict__ src,
                                             unsigned short* __restrict__ dst, int n) {
    int i = (blockIdx.x * 256 + threadIdx.x) * 8;
    if (i < n) {
        float4 a0 = *reinterpret_cast<const float4*>(src + i);
        float4 a1 = *reinterpret_cast<const float4*>(src + i + 4);
        unsigned short o[8] = { f2h(a0.x), f2h(a0.y), f2h(a0.z), f2h(a0.w),
                                f2h(a1.x), f2h(a1.y), f2h(a1.z), f2h(a1.w) };
        *reinterpret_cast<uint4*>(dst + i) = *reinterpret_cast<const uint4*>(o);
    }
}

// ---------------- persistent recurrence ----------------
// 64 WGs x 512 threads. team = wg&7 (batch), slice = wg>>3 (512 rows).
// Exchange: tagged word u32 = (epoch<<16)|f16(h), DUAL published:
//   (1) plain store to hxL  -> write-through L1, lands in this XCD's L2.
//       With team = wg&7 and round-robin dispatch, all team WGs share the
//       XCD, so consumers' sc0 loads (L1-bypass, L2-served) see it in
//       ~L2-hit latency. FAST PATH.
//   (2) relaxed agent store to hxG (separate buffer) -> MALL-visible
//       regardless of WG placement. GUARANTEED PATH.
// Consume: one coalesced sc0 pull (4 u64/thread) of hxL, retried <=64x;
// on exhaustion, poll hxG at agent scope until fresh (terminates by r7's
// proven protocol). Correctness therefore does NOT depend on the
// WG->XCD mapping; only speed does (G16-safe).
// Overwrite safety (parity induction, as r7): producer publishes e only
// after fully pulling e-1, which required every producer to have published
// e-1, hence every WG consumed e-2 (same-parity buffer) already.
// hxL/hxG memset each launch -> replay-safe.

__global__ __launch_bounds__(512) void k_steps(const int* __restrict__ rowptr,
                                               const unsigned* __restrict__ csr,
                                               const float* __restrict__ W_in,
                                               const int* __restrict__ x,
                                               const float* __restrict__ a,
                                               unsigned short* __restrict__ Hb,
                                               unsigned* __restrict__ hxL,
                                               unsigned* __restrict__ hxG) {
    __shared__ float plane[4096];                       // 16 KB, identity layout
    __shared__ __align__(16) unsigned lcsr[CSR_CAP];    // 72 KB
    __shared__ int ltok[T_STEPS];                       // 1 KB

    int wg = blockIdx.x;
    int tid = threadIdx.x;
    int team = wg & 7;
    int slice = wg >> 3;
    int r_own = slice * ROWS_PS + tid;

    if (tid < T_STEPS) ltok[tid] = x[team * T_STEPS + tid];

    int j0 = rowptr[slice * ROWS_PS];
    int j1 = rowptr[slice * ROWS_PS + ROWS_PS];
    int cntE = j1 - j0;
    if (cntE > CSR_CAP) cntE = CSR_CAP;
    {
        const uint4* src = reinterpret_cast<const uint4*>(csr + j0);
        int n4 = cntE >> 2;
        for (int k = tid; k < n4; k += 512)
            reinterpret_cast<uint4*>(lcsr)[k] = src[k];
    }
    for (int k = tid; k < 4096; k += 512) plane[k] = 0.f;

    int js = rowptr[r_own] - j0;
    int je = rowptr[r_own + 1] - j0;
    if (js > CSR_CAP) js = CSR_CAP;
    if (je > CSR_CAP) je = CSR_CAP;
    float av = a[r_own];
    float oma = 1.f - av;
    int cb = tid * 4;                    // u64 chunk base: rows 8*tid..8*tid+7
    __syncthreads();

    float u_cur = W_in[(size_t)ltok[0] * N_RES + r_own];

    for (int t = 0; t < T_STEPS; ++t) {
        float acc = 0.f;
        for (int j = js; j < je; j += 4) {
            uint4 e4 = *reinterpret_cast<const uint4*>(lcsr + j);
            unsigned ee[4] = { e4.x, e4.y, e4.z, e4.w };
#pragma unroll
            for (int q = 0; q < 4; ++q) {
                float g = *reinterpret_cast<const float*>(
                    reinterpret_cast<const char*>(plane) + (ee[q] >> 16));
                acc += h2f((unsigned short)(ee[q] & 0xffffu)) * g;
            }
        }
        float hold = plane[r_own];
        float pre = u_cur + acc;
        pre = fminf(fmaxf(pre, -10.f), 10.f);
        float ex = __expf(2.f * pre);
        float th = 1.f - 2.f / (ex + 1.f);
        float hv = oma * hold + av * th;
        unsigned short hv16 = f2h(hv);

        if (t == T_STEPS - 1) {
            Hb[((size_t)(team * T_STEPS + t) << 12) + r_own] = hv16;
            break;
        }

        unsigned e = (unsigned)(t + 1);
        size_t pofs = (((size_t)(e & 1u) * TEAMS + team) << 12);
        unsigned* xL = hxL + pofs;
        unsigned* xG = hxG + pofs;
        unsigned tagged = (e << 16) | (unsigned)hv16;

        // dual publish: L2-local fast copy + agent-scope guaranteed copy
        __hip_atomic_store(xL + r_own, tagged,
                           __ATOMIC_RELAXED, __HIP_MEMORY_SCOPE_WORKGROUP);
        __hip_atomic_store(xG + r_own, tagged,
                           __ATOMIC_RELAXED, __HIP_MEMORY_SCOPE_AGENT);

        // off-critical-path work in the publish shadow
        float u_nxt = W_in[(size_t)ltok[t + 1] * N_RES + r_own];
        Hb[((size_t)(team * T_STEPS + t) << 12) + r_own] = hv16;

        // fast-path pull: 4 coalesced u64 sc0 loads (L1-bypass, L2-served)
        unsigned long long g0, g1, g2, g3;
        const char* pL = reinterpret_cast<const char*>(xL) + (size_t)cb * 8;
#define PULL4_SC0()                                              \
        asm volatile(                                            \
            "global_load_dwordx2 %0, %4, off sc0\n\t"            \
            "global_load_dwordx2 %1, %4, off offset:8 sc0\n\t"   \
            "global_load_dwordx2 %2, %4, off offset:16 sc0\n\t"  \
            "global_load_dwordx2 %3, %4, off offset:24 sc0\n\t"  \
            "s_waitcnt vmcnt(0)"                                 \
            : "=v"(g0), "=v"(g1), "=v"(g2), "=v"(g3)             \
            : "v"(pL) : "memory")
#define TAGOK(g) ((((unsigned)((g) >> 16) & 0xffffu) == e) && ((unsigned)((g) >> 48) == e))

        PULL4_SC0();
        int tries = 0;
        while (!(TAGOK(g0) && TAGOK(g1) && TAGOK(g2) && TAGOK(g3))) {
            if (++tries > 64) break;
            PULL4_SC0();
        }
        if (tries > 64) {
            // guaranteed path: agent-scope poll of hxG (always visible)
            const unsigned long long* xG64 =
                reinterpret_cast<const unsigned long long*>(xG) + cb;
            for (;;) {
                g0 = __hip_atomic_load(xG64 + 0, __ATOMIC_RELAXED, __HIP_MEMORY_SCOPE_AGENT);
                g1 = __hip_atomic_load(xG64 + 1, __ATOMIC_RELAXED, __HIP_MEMORY_SCOPE_AGENT);
                g2 = __hip_atomic_load(xG64 + 2, __ATOMIC_RELAXED, __HIP_MEMORY_SCOPE_AGENT);
                g3 = __hip_atomic_load(xG64 + 3, __ATOMIC_RELAXED, __HIP_MEMORY_SCOPE_AGENT);
                if (TAGOK(g0) && TAGOK(g1) && TAGOK(g2) && TAGOK(g3)) break;
            }
        }
#undef PULL4_SC0
#undef TAGOK

        __syncthreads();            // all gathers from old plane done
        {
            float2 v;
            v.x = h2f((unsigned short)(g0 & 0xffffu));
            v.y = h2f((unsigned short)((g0 >> 32) & 0xffffu));
            *reinterpret_cast<float2*>(&plane[8 * tid + 0]) = v;
            v.x = h2f((unsigned short)(g1 & 0xffffu));
            v.y = h2f((unsigned short)((g1 >> 32) & 0xffffu));
            *reinterpret_cast<float2*>(&plane[8 * tid + 2]) = v;
            v.x = h2f((unsigned short)(g2 & 0xffffu));
            v.y = h2f((unsigned short)((g2 >> 32) & 0xffffu));
            *reinterpret_cast<float2*>(&plane[8 * tid + 4]) = v;
            v.x = h2f((unsigned short)(g3 & 0xffffu));
            v.y = h2f((unsigned short)((g3 >> 32) & 0xffffu));
            *reinterpret_cast<float2*>(&plane[8 * tid + 6]) = v;
        }
        u_cur = u_nxt;
        __syncthreads();            // new plane ready
    }
}

// ---------------- GEMM1: Rbh(2048x512,f16) = Hb(2048x4096,f16) @ Bwh^T ----------------

__global__ __launch_bounds__(512) void k_gemm1(const unsigned short* __restrict__ Hb,
                                               const unsigned short* __restrict__ Bwh,
                                               unsigned short* __restrict__ Rbh) {
    int lane = threadIdx.x & 63, wave = threadIdx.x >> 6;
    int wm = wave >> 1, wn = wave & 1;
    int row0 = blockIdx.y * 128;
    int col0 = blockIdx.x * 128 + wn * 64;
    int rA = lane & 15, kA = (lane >> 4) * 8;
    v4f acc[2][4];
    for (int s = 0; s < 2; ++s)
        for (int f = 0; f < 4; ++f)
            acc[s][f] = (v4f){0.f, 0.f, 0.f, 0.f};

    for (int k0 = 0; k0 < N_RES; k0 += 32) {
        v8h af[2];
#pragma unroll
        for (int s = 0; s < 2; ++s) {
            int r = row0 + (wm * 2 + s) * 16 + rA;
            af[s] = *reinterpret_cast<const v8h*>(Hb + (size_t)r * N_RES + k0 + kA);
        }
        v8h bf[4];
#pragma unroll
        for (int f = 0; f < 4; ++f) {
            int c = col0 + f * 16 + rA;
            bf[f] = *reinterpret_cast<const v8h*>(Bwh + (size_t)c * N_RES + k0 + kA);
        }
#pragma unroll
        for (int s = 0; s < 2; ++s)
#pragma unroll
            for (int f = 0; f < 4; ++f)
                acc[s][f] = __builtin_amdgcn_mfma_f32_16x16x32_f16(af[s], bf[f], acc[s][f], 0, 0, 0);
    }
#pragma unroll
    for (int s = 0; s < 2; ++s)
#pragma unroll
        for (int f = 0; f < 4; ++f) {
            int col = col0 + f * 16 + (lane & 15);
#pragma unroll
            for (int r = 0; r < 4; ++r) {
                int row = row0 + (wm * 2 + s) * 16 + (lane >> 4) * 4 + r;
                Rbh[(size_t)row * R_OUT + col] = f2h(acc[s][f][r]);
            }
        }
}

// ---------------- GEMM2: out(2048x32000,f32) = Rbh(f16) @ Awh^T + Ab ----------------

__global__ __launch_bounds__(512) void k_gemm2(const unsigned short* __restrict__ Rbh,
                                               const unsigned short* __restrict__ Awh,
                                               const float* __restrict__ Ab,
                                               float* __restrict__ out) {
    int lane = threadIdx.x & 63, wave = threadIdx.x >> 6;
    int wm = wave >> 1, wn = wave & 1;
    int row0 = blockIdx.y * 256;
    int col0 = blockIdx.x * 128 + wn * 64;
    int rA = lane & 15, kA = (lane >> 4) * 8;
    v4f acc[4][4];
    for (int s = 0; s < 4; ++s)
        for (int f = 0; f < 4; ++f)
            acc[s][f] = (v4f){0.f, 0.f, 0.f, 0.f};

    for (int k0 = 0; k0 < R_OUT; k0 += 32) {
        v8h af[4];
#pragma unroll
        for (int s = 0; s < 4; ++s) {
            int r = row0 + (wm * 4 + s) * 16 + rA;
            af[s] = *reinterpret_cast<const v8h*>(Rbh + (size_t)r * R_OUT + k0 + kA);
        }
        v8h bf[4];
#pragma unroll
        for (int f = 0; f < 4; ++f) {
            int c = col0 + f * 16 + rA;
            bf[f] = *reinterpret_cast<const v8h*>(Awh + (size_t)c * R_OUT + k0 + kA);
        }
#pragma unroll
        for (int s = 0; s < 4; ++s)
#pragma unroll
            for (int f = 0; f < 4; ++f)
                acc[s][f] = __builtin_amdgcn_mfma_f32_16x16x32_f16(af[s], bf[f], acc[s][f], 0, 0, 0);
    }
#pragma unroll
    for (int f = 0; f < 4; ++f) {
        int col = col0 + f * 16 + (lane & 15);
        float bias = Ab[col];
#pragma unroll
        for (int s = 0; s < 4; ++s) {
#pragma unroll
            for (int r = 0; r < 4; ++r) {
                int row = row0 + (wm * 4 + s) * 16 + (lane >> 4) * 4 + r;
                out[(size_t)row * VOCAB + col] = acc[s][f][r] + bias;
            }
        }
    }
}

// ---------------- host launch ----------------

extern "C" void kernel_launch(void* const* d_in, const int* in_sizes, int n_in,
                              void* d_out, int out_size, void* d_ws, size_t ws_size,
                              hipStream_t stream) {
    const int*   x        = (const int*)d_in[0];
    const float* W_in     = (const float*)d_in[1];
    const int*   rec_rows = (const int*)d_in[2];
    const int*   rec_cols = (const int*)d_in[3];
    const float* rec_vals = (const float*)d_in[4];
    const float* a        = (const float*)d_in[5];
    const float* B_w      = (const float*)d_in[6];
    const float* A_w      = (const float*)d_in[7];
    const float* A_b      = (const float*)d_in[8];
    float* out = (float*)d_out;

    char* w = (char*)d_ws;
    size_t off = 0;
    auto alloc = [&](size_t bytes) { void* p = w + off; off = (off + bytes + 255) & ~(size_t)255; return p; };

    unsigned short* Hb     = (unsigned short*)alloc((size_t)2048 * N_RES * 2);   // 16.8 MB
    unsigned short* Rbh    = (unsigned short*)alloc((size_t)2048 * R_OUT * 2);   // 2.1 MB
    unsigned short* Bwh    = (unsigned short*)alloc((size_t)R_OUT * N_RES * 2);  // 4.2 MB
    unsigned short* Awh    = (unsigned short*)alloc((size_t)VOCAB * R_OUT * 2);  // 32.8 MB
    unsigned*       csr    = (unsigned*)alloc((size_t)NNZ_CAP * 4);              // 655 KB
    int*            rowptr = (int*)alloc(4097 * 4);
    int*            cnt    = (int*)alloc(4096 * 4);
    int*            cursor = (int*)alloc(4096 * 4);
    unsigned*       hxL    = (unsigned*)alloc((size_t)2 * TEAMS * 4096 * 4);     // 256 KB
    unsigned*       hxG    = (unsigned*)alloc((size_t)2 * TEAMS * 4096 * 4);     // 256 KB

    hipMemsetAsync(csr, 0, (size_t)NNZ_CAP * 4, stream);
    hipMemsetAsync(cnt, 0, 4096 * 4, stream);
    hipMemsetAsync(hxL, 0, (size_t)2 * TEAMS * 4096 * 4, stream);
    hipMemsetAsync(hxG, 0, (size_t)2 * TEAMS * 4096 * 4, stream);

    k_hist<<<(NNZ + 255) / 256, 256, 0, stream>>>(rec_rows, cnt);
    k_scan<<<1, 1024, 0, stream>>>(cnt, rowptr, cursor);
    k_fill<<<(NNZ + 255) / 256, 256, 0, stream>>>(rec_rows, rec_cols, rec_vals, cursor, csr);

    k_cvt<<<(R_OUT * N_RES / 8 + 255) / 256, 256, 0, stream>>>(B_w, Bwh, R_OUT * N_RES);
    k_cvt<<<(VOCAB * R_OUT / 8 + 255) / 256, 256, 0, stream>>>(A_w, Awh, VOCAB * R_OUT);

    k_steps<<<NWG, 512, 0, stream>>>(rowptr, csr, W_in, x, a, Hb, hxL, hxG);

    k_gemm1<<<dim3(R_OUT / 128, 2048 / 128), 512, 0, stream>>>(Hb, Bwh, Rbh);
    k_gemm2<<<dim3(VOCAB / 128, 2048 / 256), 512, 0, stream>>>(Rbh, Awh, A_b, out);
}

// Round 9
// 1502.588 us; speedup vs baseline: 3.1964x; 3.1964x over previous
//
#include <hip/hip_runtime.h>
#include <hip/hip_bf16.h>
#include <stdint.h>

#define N_RES 4096
#define BATCH 8
#define T_STEPS 256
#define VOCAB 32000
#define R_OUT 512
#define NNZ 131072
#define NNZ_CAP 163840
#define TEAMS 8             // one per batch
#define SLICES 16           // WGs per team
#define ROWS_PS 256         // rows per WG
#define NWG (TEAMS*SLICES)  // 128
#define CSR_CAP 10240       // entries per slice in LDS (mean ~9088, +11 sigma)

typedef _Float16 v8h __attribute__((ext_vector_type(8)));
typedef float v4f __attribute__((ext_vector_type(4)));

static __device__ __forceinline__ unsigned short f2h(float f) {
    _Float16 h = (_Float16)f;
    unsigned short u;
    __builtin_memcpy(&u, &h, 2);
    return u;
}
static __device__ __forceinline__ float h2f(unsigned short u) {
    _Float16 h;
    __builtin_memcpy(&h, &u, 2);
    return (float)h;
}

// ---------------- fused init: zero csr, cnt, flags (one graph node) ----------------

#define FLAG_WORDS (TEAMS * SLICES * 32)        // 4096 u32
#define INIT_WORDS (NNZ_CAP + 4096 + FLAG_WORDS)

__global__ __launch_bounds__(256) void k_init(unsigned* __restrict__ csr,
                                              int* __restrict__ cnt,
                                              unsigned* __restrict__ flags) {
    int i = blockIdx.x * 256 + threadIdx.x;
    if (i < NNZ_CAP) csr[i] = 0u;
    else if (i < NNZ_CAP + 4096) cnt[i - NNZ_CAP] = 0;
    else if (i < INIT_WORDS) flags[i - NNZ_CAP - 4096] = 0u;
}

// ---------------- CSR build ----------------

__global__ __launch_bounds__(256) void k_hist(const int* __restrict__ rows,
                                              int* __restrict__ cnt) {
    int i = blockIdx.x * 256 + threadIdx.x;
    if (i < NNZ) atomicAdd(&cnt[rows[i]], 1);
}

// padded scan: each row's span rounded up to multiple of 8
__global__ __launch_bounds__(1024) void k_scan(const int* __restrict__ cnt,
                                               int* __restrict__ row_ptr,
                                               int* __restrict__ cursor) {
    __shared__ int sm[1024];
    int t = threadIdx.x;
    int base = t * 4;
    int c0 = (cnt[base] + 7) & ~7;
    int c1 = (cnt[base + 1] + 7) & ~7;
    int c2 = (cnt[base + 2] + 7) & ~7;
    int c3 = (cnt[base + 3] + 7) & ~7;
    int s = c0 + c1 + c2 + c3;
    sm[t] = s;
    __syncthreads();
    for (int off = 1; off < 1024; off <<= 1) {
        int v = (t >= off) ? sm[t - off] : 0;
        __syncthreads();
        sm[t] += v;
        __syncthreads();
    }
    int run = sm[t] - s;
    row_ptr[base] = run;     cursor[base] = run;     run += c0;
    row_ptr[base + 1] = run; cursor[base + 1] = run; run += c1;
    row_ptr[base + 2] = run; cursor[base + 2] = run; run += c2;
    row_ptr[base + 3] = run; cursor[base + 3] = run; run += c3;
    if (t == 1023) row_ptr[4096] = run;
}

// packed CSR entry: swizzled plane byte-offset in hi16, f16 value in lo16.
// plane index p(col) = ((col&15)<<8) | (col>>4); byte off = p*4.
__global__ __launch_bounds__(256) void k_fill(const int* __restrict__ rows,
                                              const int* __restrict__ cols,
                                              const float* __restrict__ vals,
                                              int* __restrict__ cursor,
                                              unsigned* __restrict__ csr) {
    int i = blockIdx.x * 256 + threadIdx.x;
    if (i < NNZ) {
        int r = rows[i];
        int c = cols[i];
        int p = atomicAdd(&cursor[r], 1);
        unsigned off = ((unsigned)(c & 15) << 10) | ((unsigned)(c >> 4) << 2);
        csr[p] = (off << 16) | (unsigned)f2h(vals[i]);
    }
}

// ---------------- fused f32 -> f16 convert: B_w then A_w (one node) ----------------

#define NB8 (R_OUT * N_RES / 8)     // 262144 B_w octets
#define NA8 (VOCAB * R_OUT / 8)     // 2048000 A_w octets

__global__ __launch_bounds__(256) void k_cvt2(const float* __restrict__ Bw,
                                              unsigned short* __restrict__ Bwh,
                                              const float* __restrict__ Aw,
                                              unsigned short* __restrict__ Awh) {
    int i = blockIdx.x * 256 + threadIdx.x;
    const float* src;
    unsigned short* dst;
    int j;
    if (i < NB8) { src = Bw; dst = Bwh; j = i * 8; }
    else if (i < NB8 + NA8) { src = Aw; dst = Awh; j = (i - NB8) * 8; }
    else return;
    float4 a0 = *reinterpret_cast<const float4*>(src + j);
    float4 a1 = *reinterpret_cast<const float4*>(src + j + 4);
    unsigned short o[8] = { f2h(a0.x), f2h(a0.y), f2h(a0.z), f2h(a0.w),
                            f2h(a1.x), f2h(a1.y), f2h(a1.z), f2h(a1.w) };
    *reinterpret_cast<uint4*>(dst + j) = *reinterpret_cast<const uint4*>(o);
}

// ---------------- persistent recurrence (r3 protocol, verbatim) ----------------
// 128 WGs x 256 threads. team = wg&7 (batch), slice = wg>>3 (256 rows).
// Per-team exchange: hx[par][team][4096 f16] published as u64 chunks via
// relaxed agent atomics; per-WG epoch flag (128B apart) after vmcnt(0).
// LDS h-plane is f32, bank-swizzled; swizzle baked into CSR offsets.

__global__ __launch_bounds__(256) void k_steps(const int* __restrict__ rowptr,
                                               const unsigned* __restrict__ csr,
                                               const float* __restrict__ W_in,
                                               const int* __restrict__ x,
                                               const float* __restrict__ a,
                                               unsigned short* __restrict__ Hb,
                                               unsigned long long* __restrict__ hx,
                                               unsigned* __restrict__ flags) {
    __shared__ float plane[4096];                       // 16 KB, swizzled
    __shared__ __align__(16) unsigned lcsr[CSR_CAP];    // 40 KB
    __shared__ unsigned long long stage64[64];          // 512 B
    __shared__ int ltok[T_STEPS];                       // 1 KB

    int wg = blockIdx.x;
    int tid = threadIdx.x;
    int team = wg & 7;
    int slice = wg >> 3;
    int r_own = slice * ROWS_PS + tid;

    ltok[tid] = x[team * T_STEPS + tid];

    int j0 = rowptr[slice * ROWS_PS];
    int j1 = rowptr[slice * ROWS_PS + ROWS_PS];
    int cntE = j1 - j0;
    if (cntE > CSR_CAP) cntE = CSR_CAP;
    {
        const uint4* src = reinterpret_cast<const uint4*>(csr + j0);
        int n4 = cntE >> 2;
        for (int k = tid; k < n4; k += 256)
            reinterpret_cast<uint4*>(lcsr)[k] = src[k];
    }
    for (int k = tid; k < 4096; k += 256) plane[k] = 0.f;

    int js = rowptr[r_own] - j0;
    int je = rowptr[r_own + 1] - j0;
    if (js > CSR_CAP) js = CSR_CAP;
    if (je > CSR_CAP) je = CSR_CAP;
    float av = a[r_own];
    float oma = 1.f - av;
    int pown = ((r_own & 15) << 8) | (r_own >> 4);
    __syncthreads();

    float u_cur = W_in[(size_t)ltok[0] * N_RES + r_own];

    for (int t = 0; t < T_STEPS; ++t) {
        float u_nxt = 0.f;
        if (t + 1 < T_STEPS)
            u_nxt = W_in[(size_t)ltok[t + 1] * N_RES + r_own];   // long shadow

        float acc = 0.f;
        for (int j = js; j < je; j += 8) {
            uint4 e0 = *reinterpret_cast<const uint4*>(lcsr + j);
            uint4 e1 = *reinterpret_cast<const uint4*>(lcsr + j + 4);
            unsigned ee[8] = { e0.x, e0.y, e0.z, e0.w, e1.x, e1.y, e1.z, e1.w };
#pragma unroll
            for (int q = 0; q < 8; ++q) {
                float g = *reinterpret_cast<const float*>(
                    reinterpret_cast<const char*>(plane) + (ee[q] >> 16));
                acc += h2f((unsigned short)(ee[q] & 0xffffu)) * g;
            }
        }
        float hold = plane[pown];
        float pre = u_cur + acc;
        pre = fminf(fmaxf(pre, -10.f), 10.f);
        float ex = __expf(2.f * pre);
        float th = 1.f - 2.f / (ex + 1.f);
        float hv = oma * hold + av * th;
        unsigned short hv16 = f2h(hv);
        Hb[((size_t)(team * T_STEPS + t) << 12) + r_own] = hv16;
        u_cur = u_nxt;

        if (t == T_STEPS - 1) break;

        reinterpret_cast<unsigned short*>(stage64)[tid] = hv16;
        __syncthreads();
        int par = t & 1;
        unsigned long long* base = hx + ((size_t)(par * TEAMS + team)) * 1024;
        if (tid < 64) {
            unsigned long long d = stage64[tid];
            __hip_atomic_store(base + slice * 64 + tid, d,
                               __ATOMIC_RELAXED, __HIP_MEMORY_SCOPE_AGENT);
        }
        asm volatile("s_waitcnt vmcnt(0)" ::: "memory");
        __syncthreads();
        if (tid == 0)
            __hip_atomic_store(flags + (team * SLICES + slice) * 32, (unsigned)(t + 1),
                               __ATOMIC_RELAXED, __HIP_MEMORY_SCOPE_AGENT);
        if (tid < SLICES) {
            const unsigned* fp = flags + (team * SLICES + tid) * 32;
            while (__hip_atomic_load(fp, __ATOMIC_RELAXED,
                                     __HIP_MEMORY_SCOPE_AGENT) < (unsigned)(t + 1)) {}
        }
        __syncthreads();
        // pull fresh 8KB team plane, convert to swizzled f32
        const unsigned long long* src = base + tid * 4;
#pragma unroll
        for (int k = 0; k < 4; ++k) {
            unsigned long long d = __hip_atomic_load(src + k, __ATOMIC_RELAXED,
                                                     __HIP_MEMORY_SCOPE_AGENT);
            int jb = k * 4;
            plane[((jb + 0) << 8) | tid] = h2f((unsigned short)(d & 0xffffu));
            plane[((jb + 1) << 8) | tid] = h2f((unsigned short)((d >> 16) & 0xffffu));
            plane[((jb + 2) << 8) | tid] = h2f((unsigned short)((d >> 32) & 0xffffu));
            plane[((jb + 3) << 8) | tid] = h2f((unsigned short)((d >> 48) & 0xffffu));
        }
        __syncthreads();
    }
}

// ---------------- GEMM1: Rbh(2048x512,f16) = Hb(2048x4096,f16) @ Bwh^T ----------------

__global__ __launch_bounds__(512) void k_gemm1(const unsigned short* __restrict__ Hb,
                                               const unsigned short* __restrict__ Bwh,
                                               unsigned short* __restrict__ Rbh) {
    int lane = threadIdx.x & 63, wave = threadIdx.x >> 6;
    int wm = wave >> 1, wn = wave & 1;
    int row0 = blockIdx.y * 128;
    int col0 = blockIdx.x * 128 + wn * 64;
    int rA = lane & 15, kA = (lane >> 4) * 8;
    v4f acc[2][4];
    for (int s = 0; s < 2; ++s)
        for (int f = 0; f < 4; ++f)
            acc[s][f] = (v4f){0.f, 0.f, 0.f, 0.f};

    for (int k0 = 0; k0 < N_RES; k0 += 32) {
        v8h af[2];
#pragma unroll
        for (int s = 0; s < 2; ++s) {
            int r = row0 + (wm * 2 + s) * 16 + rA;
            af[s] = *reinterpret_cast<const v8h*>(Hb + (size_t)r * N_RES + k0 + kA);
        }
        v8h bf[4];
#pragma unroll
        for (int f = 0; f < 4; ++f) {
            int c = col0 + f * 16 + rA;
            bf[f] = *reinterpret_cast<const v8h*>(Bwh + (size_t)c * N_RES + k0 + kA);
        }
#pragma unroll
        for (int s = 0; s < 2; ++s)
#pragma unroll
            for (int f = 0; f < 4; ++f)
                acc[s][f] = __builtin_amdgcn_mfma_f32_16x16x32_f16(af[s], bf[f], acc[s][f], 0, 0, 0);
    }
#pragma unroll
    for (int s = 0; s < 2; ++s)
#pragma unroll
        for (int f = 0; f < 4; ++f) {
            int col = col0 + f * 16 + (lane & 15);
#pragma unroll
            for (int r = 0; r < 4; ++r) {
                int row = row0 + (wm * 2 + s) * 16 + (lane >> 4) * 4 + r;
                Rbh[(size_t)row * R_OUT + col] = f2h(acc[s][f][r]);
            }
        }
}

// ---------------- GEMM2: out(2048x32000,f32) = Rbh(f16) @ Awh^T + Ab ----------------

__global__ __launch_bounds__(512) void k_gemm2(const unsigned short* __restrict__ Rbh,
                                               const unsigned short* __restrict__ Awh,
                                               const float* __restrict__ Ab,
                                               float* __restrict__ out) {
    int lane = threadIdx.x & 63, wave = threadIdx.x >> 6;
    int wm = wave >> 1, wn = wave & 1;
    int row0 = blockIdx.x * 256;
    int col0 = blockIdx.y * 128 + wn * 64;
    int rA = lane & 15, kA = (lane >> 4) * 8;
    v4f acc[4][4];
    for (int s = 0; s < 4; ++s)
        for (int f = 0; f < 4; ++f)
            acc[s][f] = (v4f){0.f, 0.f, 0.f, 0.f};

    for (int k0 = 0; k0 < R_OUT; k0 += 32) {
        v8h af[4];
#pragma unroll
        for (int s = 0; s < 4; ++s) {
            int r = row0 + (wm * 4 + s) * 16 + rA;
            af[s] = *reinterpret_cast<const v8h*>(Rbh + (size_t)r * R_OUT + k0 + kA);
        }
        v8h bf[4];
#pragma unroll
        for (int f = 0; f < 4; ++f) {
            int c = col0 + f * 16 + rA;
            bf[f] = *reinterpret_cast<const v8h*>(Awh + (size_t)c * R_OUT + k0 + kA);
        }
#pragma unroll
        for (int s = 0; s < 4; ++s)
#pragma unroll
            for (int f = 0; f < 4; ++f)
                acc[s][f] = __builtin_amdgcn_mfma_f32_16x16x32_f16(af[s], bf[f], acc[s][f], 0, 0, 0);
    }
#pragma unroll
    for (int f = 0; f < 4; ++f) {
        int col = col0 + f * 16 + (lane & 15);
        float bias = Ab[col];
#pragma unroll
        for (int s = 0; s < 4; ++s) {
#pragma unroll
            for (int r = 0; r < 4; ++r) {
                int row = row0 + (wm * 4 + s) * 16 + (lane >> 4) * 4 + r;
                out[(size_t)row * VOCAB + col] = acc[s][f][r] + bias;
            }
        }
    }
}

// ---------------- host launch ----------------

extern "C" void kernel_launch(void* const* d_in, const int* in_sizes, int n_in,
                              void* d_out, int out_size, void* d_ws, size_t ws_size,
                              hipStream_t stream) {
    const int*   x        = (const int*)d_in[0];
    const float* W_in     = (const float*)d_in[1];
    const int*   rec_rows = (const int*)d_in[2];
    const int*   rec_cols = (const int*)d_in[3];
    const float* rec_vals = (const float*)d_in[4];
    const float* a        = (const float*)d_in[5];
    const float* B_w      = (const float*)d_in[6];
    const float* A_w      = (const float*)d_in[7];
    const float* A_b      = (const float*)d_in[8];
    float* out = (float*)d_out;

    char* w = (char*)d_ws;
    size_t off = 0;
    auto alloc = [&](size_t bytes) { void* p = w + off; off = (off + bytes + 255) & ~(size_t)255; return p; };

    unsigned short* Hb     = (unsigned short*)alloc((size_t)2048 * N_RES * 2);   // 16.8 MB
    unsigned short* Rbh    = (unsigned short*)alloc((size_t)2048 * R_OUT * 2);   // 2.1 MB
    unsigned short* Bwh    = (unsigned short*)alloc((size_t)R_OUT * N_RES * 2);  // 4.2 MB
    unsigned short* Awh    = (unsigned short*)alloc((size_t)VOCAB * R_OUT * 2);  // 32.8 MB
    unsigned*       csr    = (unsigned*)alloc((size_t)NNZ_CAP * 4);              // 655 KB
    int*            rowptr = (int*)alloc(4097 * 4);
    int*            cnt    = (int*)alloc(4096 * 4);
    int*            cursor = (int*)alloc(4096 * 4);
    unsigned long long* hx = (unsigned long long*)alloc(2 * TEAMS * 1024 * 8);   // 128 KB
    unsigned*       flags  = (unsigned*)alloc(FLAG_WORDS * 4);                   // 16 KB

    k_init<<<(INIT_WORDS + 255) / 256, 256, 0, stream>>>(csr, cnt, flags);

    k_hist<<<(NNZ + 255) / 256, 256, 0, stream>>>(rec_rows, cnt);
    k_scan<<<1, 1024, 0, stream>>>(cnt, rowptr, cursor);
    k_fill<<<(NNZ + 255) / 256, 256, 0, stream>>>(rec_rows, rec_cols, rec_vals, cursor, csr);

    k_cvt2<<<(NB8 + NA8 + 255) / 256, 256, 0, stream>>>(B_w, Bwh, A_w, Awh);

    k_steps<<<NWG, 256, 0, stream>>>(rowptr, csr, W_in, x, a, Hb, hx, flags);

    k_gemm1<<<dim3(R_OUT / 128, 2048 / 128), 512, 0, stream>>>(Hb, Bwh, Rbh);
    k_gemm2<<<dim3(2048 / 256, VOCAB / 128), 512, 0, stream>>>(Rbh, Awh, A_b, out);
}

// Round 10
// 1341.808 us; speedup vs baseline: 3.5794x; 1.1198x over previous
//
#include <hip/hip_runtime.h>
#include <hip/hip_bf16.h>
#include <stdint.h>

#define N_RES 4096
#define BATCH 8
#define T_STEPS 256
#define VOCAB 32000
#define R_OUT 512
#define NNZ 131072
#define NNZ_CAP 163840
#define TEAMS 8             // one per batch
#define SLICES 16           // WGs per team
#define ROWS_PS 256         // rows per WG
#define NWG (TEAMS*SLICES)  // 128
#define CSR_CAP 10240       // entries per slice in LDS (mean ~9088, +11 sigma)

typedef _Float16 v8h __attribute__((ext_vector_type(8)));
typedef float v4f __attribute__((ext_vector_type(4)));

static __device__ __forceinline__ unsigned short f2h(float f) {
    _Float16 h = (_Float16)f;
    unsigned short u;
    __builtin_memcpy(&u, &h, 2);
    return u;
}
static __device__ __forceinline__ float h2f(unsigned short u) {
    _Float16 h;
    __builtin_memcpy(&h, &u, 2);
    return (float)h;
}

// ---------------- fused init: zero csr, cnt, flags (one graph node) ----------------

#define FLAG_WORDS (TEAMS * SLICES * 32)        // 4096 u32
#define INIT_WORDS (NNZ_CAP + 4096 + FLAG_WORDS)

__global__ __launch_bounds__(256) void k_init(unsigned* __restrict__ csr,
                                              int* __restrict__ cnt,
                                              unsigned* __restrict__ flags) {
    int i = blockIdx.x * 256 + threadIdx.x;
    if (i < NNZ_CAP) csr[i] = 0u;
    else if (i < NNZ_CAP + 4096) cnt[i - NNZ_CAP] = 0;
    else if (i < INIT_WORDS) flags[i - NNZ_CAP - 4096] = 0u;
}

// ---------------- CSR build ----------------

__global__ __launch_bounds__(256) void k_hist(const int* __restrict__ rows,
                                              int* __restrict__ cnt) {
    int i = blockIdx.x * 256 + threadIdx.x;
    if (i < NNZ) atomicAdd(&cnt[rows[i]], 1);
}

// padded scan: each row's span rounded up to multiple of 8
__global__ __launch_bounds__(1024) void k_scan(const int* __restrict__ cnt,
                                               int* __restrict__ row_ptr,
                                               int* __restrict__ cursor) {
    __shared__ int sm[1024];
    int t = threadIdx.x;
    int base = t * 4;
    int c0 = (cnt[base] + 7) & ~7;
    int c1 = (cnt[base + 1] + 7) & ~7;
    int c2 = (cnt[base + 2] + 7) & ~7;
    int c3 = (cnt[base + 3] + 7) & ~7;
    int s = c0 + c1 + c2 + c3;
    sm[t] = s;
    __syncthreads();
    for (int off = 1; off < 1024; off <<= 1) {
        int v = (t >= off) ? sm[t - off] : 0;
        __syncthreads();
        sm[t] += v;
        __syncthreads();
    }
    int run = sm[t] - s;
    row_ptr[base] = run;     cursor[base] = run;     run += c0;
    row_ptr[base + 1] = run; cursor[base + 1] = run; run += c1;
    row_ptr[base + 2] = run; cursor[base + 2] = run; run += c2;
    row_ptr[base + 3] = run; cursor[base + 3] = run; run += c3;
    if (t == 1023) row_ptr[4096] = run;
}

// packed CSR entry: swizzled plane byte-offset in hi16, f16 value in lo16.
// plane index p(col) = ((col&15)<<8) | (col>>4); byte off = p*4.
__global__ __launch_bounds__(256) void k_fill(const int* __restrict__ rows,
                                              const int* __restrict__ cols,
                                              const float* __restrict__ vals,
                                              int* __restrict__ cursor,
                                              unsigned* __restrict__ csr) {
    int i = blockIdx.x * 256 + threadIdx.x;
    if (i < NNZ) {
        int r = rows[i];
        int c = cols[i];
        int p = atomicAdd(&cursor[r], 1);
        unsigned off = ((unsigned)(c & 15) << 10) | ((unsigned)(c >> 4) << 2);
        csr[p] = (off << 16) | (unsigned)f2h(vals[i]);
    }
}

// ---------------- fused f32 -> f16 convert: B_w then A_w (one node) ----------------

#define NB8 (R_OUT * N_RES / 8)     // 262144 B_w octets
#define NA8 (VOCAB * R_OUT / 8)     // 2048000 A_w octets

__global__ __launch_bounds__(256) void k_cvt2(const float* __restrict__ Bw,
                                              unsigned short* __restrict__ Bwh,
                                              const float* __restrict__ Aw,
                                              unsigned short* __restrict__ Awh) {
    int i = blockIdx.x * 256 + threadIdx.x;
    const float* src;
    unsigned short* dst;
    int j;
    if (i < NB8) { src = Bw; dst = Bwh; j = i * 8; }
    else if (i < NB8 + NA8) { src = Aw; dst = Awh; j = (i - NB8) * 8; }
    else return;
    float4 a0 = *reinterpret_cast<const float4*>(src + j);
    float4 a1 = *reinterpret_cast<const float4*>(src + j + 4);
    unsigned short o[8] = { f2h(a0.x), f2h(a0.y), f2h(a0.z), f2h(a0.w),
                            f2h(a1.x), f2h(a1.y), f2h(a1.z), f2h(a1.w) };
    *reinterpret_cast<uint4*>(dst + j) = *reinterpret_cast<const uint4*>(o);
}

// ---------------- persistent recurrence (r3 protocol, verbatim — DO NOT TOUCH) ----------------

__global__ __launch_bounds__(256) void k_steps(const int* __restrict__ rowptr,
                                               const unsigned* __restrict__ csr,
                                               const float* __restrict__ W_in,
                                               const int* __restrict__ x,
                                               const float* __restrict__ a,
                                               unsigned short* __restrict__ Hb,
                                               unsigned long long* __restrict__ hx,
                                               unsigned* __restrict__ flags) {
    __shared__ float plane[4096];                       // 16 KB, swizzled
    __shared__ __align__(16) unsigned lcsr[CSR_CAP];    // 40 KB
    __shared__ unsigned long long stage64[64];          // 512 B
    __shared__ int ltok[T_STEPS];                       // 1 KB

    int wg = blockIdx.x;
    int tid = threadIdx.x;
    int team = wg & 7;
    int slice = wg >> 3;
    int r_own = slice * ROWS_PS + tid;

    ltok[tid] = x[team * T_STEPS + tid];

    int j0 = rowptr[slice * ROWS_PS];
    int j1 = rowptr[slice * ROWS_PS + ROWS_PS];
    int cntE = j1 - j0;
    if (cntE > CSR_CAP) cntE = CSR_CAP;
    {
        const uint4* src = reinterpret_cast<const uint4*>(csr + j0);
        int n4 = cntE >> 2;
        for (int k = tid; k < n4; k += 256)
            reinterpret_cast<uint4*>(lcsr)[k] = src[k];
    }
    for (int k = tid; k < 4096; k += 256) plane[k] = 0.f;

    int js = rowptr[r_own] - j0;
    int je = rowptr[r_own + 1] - j0;
    if (js > CSR_CAP) js = CSR_CAP;
    if (je > CSR_CAP) je = CSR_CAP;
    float av = a[r_own];
    float oma = 1.f - av;
    int pown = ((r_own & 15) << 8) | (r_own >> 4);
    __syncthreads();

    float u_cur = W_in[(size_t)ltok[0] * N_RES + r_own];

    for (int t = 0; t < T_STEPS; ++t) {
        float u_nxt = 0.f;
        if (t + 1 < T_STEPS)
            u_nxt = W_in[(size_t)ltok[t + 1] * N_RES + r_own];   // long shadow

        float acc = 0.f;
        for (int j = js; j < je; j += 8) {
            uint4 e0 = *reinterpret_cast<const uint4*>(lcsr + j);
            uint4 e1 = *reinterpret_cast<const uint4*>(lcsr + j + 4);
            unsigned ee[8] = { e0.x, e0.y, e0.z, e0.w, e1.x, e1.y, e1.z, e1.w };
#pragma unroll
            for (int q = 0; q < 8; ++q) {
                float g = *reinterpret_cast<const float*>(
                    reinterpret_cast<const char*>(plane) + (ee[q] >> 16));
                acc += h2f((unsigned short)(ee[q] & 0xffffu)) * g;
            }
        }
        float hold = plane[pown];
        float pre = u_cur + acc;
        pre = fminf(fmaxf(pre, -10.f), 10.f);
        float ex = __expf(2.f * pre);
        float th = 1.f - 2.f / (ex + 1.f);
        float hv = oma * hold + av * th;
        unsigned short hv16 = f2h(hv);
        Hb[((size_t)(team * T_STEPS + t) << 12) + r_own] = hv16;
        u_cur = u_nxt;

        if (t == T_STEPS - 1) break;

        reinterpret_cast<unsigned short*>(stage64)[tid] = hv16;
        __syncthreads();
        int par = t & 1;
        unsigned long long* base = hx + ((size_t)(par * TEAMS + team)) * 1024;
        if (tid < 64) {
            unsigned long long d = stage64[tid];
            __hip_atomic_store(base + slice * 64 + tid, d,
                               __ATOMIC_RELAXED, __HIP_MEMORY_SCOPE_AGENT);
        }
        asm volatile("s_waitcnt vmcnt(0)" ::: "memory");
        __syncthreads();
        if (tid == 0)
            __hip_atomic_store(flags + (team * SLICES + slice) * 32, (unsigned)(t + 1),
                               __ATOMIC_RELAXED, __HIP_MEMORY_SCOPE_AGENT);
        if (tid < SLICES) {
            const unsigned* fp = flags + (team * SLICES + tid) * 32;
            while (__hip_atomic_load(fp, __ATOMIC_RELAXED,
                                     __HIP_MEMORY_SCOPE_AGENT) < (unsigned)(t + 1)) {}
        }
        __syncthreads();
        // pull fresh 8KB team plane, convert to swizzled f32
        const unsigned long long* src = base + tid * 4;
#pragma unroll
        for (int k = 0; k < 4; ++k) {
            unsigned long long d = __hip_atomic_load(src + k, __ATOMIC_RELAXED,
                                                     __HIP_MEMORY_SCOPE_AGENT);
            int jb = k * 4;
            plane[((jb + 0) << 8) | tid] = h2f((unsigned short)(d & 0xffffu));
            plane[((jb + 1) << 8) | tid] = h2f((unsigned short)((d >> 16) & 0xffffu));
            plane[((jb + 2) << 8) | tid] = h2f((unsigned short)((d >> 32) & 0xffffu));
            plane[((jb + 3) << 8) | tid] = h2f((unsigned short)((d >> 48) & 0xffffu));
        }
        __syncthreads();
    }
}

// ---------------- staged-GEMM common: 128x32 f16 tile via global_load_lds ----------------

static __device__ __forceinline__ void stage128x32(const _Float16* __restrict__ g,
                                                   int ld, int row0, int k0,
                                                   _Float16* lds, int wave, int lane) {
#pragma unroll
    for (int q = 0; q < 2; ++q) {
        int i = wave * 128 + q * 64 + lane;
        const _Float16* src = g + (size_t)(row0 + (i >> 2)) * ld + k0 + (i & 3) * 8;
        int loff = __builtin_amdgcn_readfirstlane((wave * 128 + q * 64) * 16);
        __builtin_amdgcn_global_load_lds(
            (const __attribute__((address_space(1))) void*)src,
            (__attribute__((address_space(3))) void*)((char*)lds + loff),
            16, 0, 0);
    }
}

// ---------------- GEMM1: Rbh(2048x512,f16) = Hb(2048x4096,f16) @ Bwh^T ----------------
// 128x128 tile, 256 thr (4 waves 2x2), BK=32 double-buffered LDS. grid (4, 16).

__global__ __launch_bounds__(256) void k_gemm1(const _Float16* __restrict__ Hb,
                                               const _Float16* __restrict__ Bwh,
                                               unsigned short* __restrict__ Rbh) {
    __shared__ _Float16 As[2][128 * 32];
    __shared__ _Float16 Bs[2][128 * 32];
    int tid = threadIdx.x, lane = tid & 63, wave = tid >> 6;
    int wm = wave >> 1, wn = wave & 1;
    int col0 = blockIdx.x * 128;
    int row0 = blockIdx.y * 128;
    int rA = lane & 15, kA = (lane >> 4) * 8;
    v4f acc[4][4];
#pragma unroll
    for (int s = 0; s < 4; ++s)
#pragma unroll
        for (int f = 0; f < 4; ++f) acc[s][f] = (v4f){0.f, 0.f, 0.f, 0.f};

    stage128x32(Hb,  N_RES, row0, 0, As[0], wave, lane);
    stage128x32(Bwh, N_RES, col0, 0, Bs[0], wave, lane);
    const int NIT = N_RES / 32;   // 128
    for (int it = 0; it < NIT; ++it) {
        int cur = it & 1;
        __syncthreads();
        asm volatile("s_waitcnt vmcnt(0)" ::: "memory");
        __syncthreads();
        if (it + 1 < NIT) {
            stage128x32(Hb,  N_RES, row0, (it + 1) * 32, As[cur ^ 1], wave, lane);
            stage128x32(Bwh, N_RES, col0, (it + 1) * 32, Bs[cur ^ 1], wave, lane);
        }
        v8h af[4], bf[4];
#pragma unroll
        for (int s = 0; s < 4; ++s)
            af[s] = *reinterpret_cast<const v8h*>(&As[cur][(wm * 64 + s * 16 + rA) * 32 + kA]);
#pragma unroll
        for (int f = 0; f < 4; ++f)
            bf[f] = *reinterpret_cast<const v8h*>(&Bs[cur][(wn * 64 + f * 16 + rA) * 32 + kA]);
#pragma unroll
        for (int s = 0; s < 4; ++s)
#pragma unroll
            for (int f = 0; f < 4; ++f)
                acc[s][f] = __builtin_amdgcn_mfma_f32_16x16x32_f16(af[s], bf[f], acc[s][f], 0, 0, 0);
    }
#pragma unroll
    for (int f = 0; f < 4; ++f) {
        int col = col0 + wn * 64 + f * 16 + (lane & 15);
#pragma unroll
        for (int s = 0; s < 4; ++s)
#pragma unroll
            for (int r = 0; r < 4; ++r) {
                int row = row0 + wm * 64 + s * 16 + (lane >> 4) * 4 + r;
                Rbh[(size_t)row * R_OUT + col] = f2h(acc[s][f][r]);
            }
    }
}

// ---------------- GEMM2: out(2048x32000,f32) = Rbh(f16) @ Awh^T + Ab ----------------
// 128x128 tile, BK=32 double-buffered LDS, LDS-transposed float4 epilogue.
// grid (250, 16).

__global__ __launch_bounds__(256) void k_gemm2(const _Float16* __restrict__ Rbh,
                                               const _Float16* __restrict__ Awh,
                                               const float* __restrict__ Ab,
                                               float* __restrict__ out) {
    __shared__ _Float16 As[2][128 * 32];
    __shared__ _Float16 Bs[2][128 * 32];
    int tid = threadIdx.x, lane = tid & 63, wave = tid >> 6;
    int wm = wave >> 1, wn = wave & 1;
    int col0 = blockIdx.x * 128;
    int row0 = blockIdx.y * 128;
    int rA = lane & 15, kA = (lane >> 4) * 8;
    v4f acc[4][4];
#pragma unroll
    for (int s = 0; s < 4; ++s)
#pragma unroll
        for (int f = 0; f < 4; ++f) acc[s][f] = (v4f){0.f, 0.f, 0.f, 0.f};

    stage128x32(Rbh, R_OUT, row0, 0, As[0], wave, lane);
    stage128x32(Awh, R_OUT, col0, 0, Bs[0], wave, lane);
    const int NIT = R_OUT / 32;   // 16
    for (int it = 0; it < NIT; ++it) {
        int cur = it & 1;
        __syncthreads();
        asm volatile("s_waitcnt vmcnt(0)" ::: "memory");
        __syncthreads();
        if (it + 1 < NIT) {
            stage128x32(Rbh, R_OUT, row0, (it + 1) * 32, As[cur ^ 1], wave, lane);
            stage128x32(Awh, R_OUT, col0, (it + 1) * 32, Bs[cur ^ 1], wave, lane);
        }
        v8h af[4], bf[4];
#pragma unroll
        for (int s = 0; s < 4; ++s)
            af[s] = *reinterpret_cast<const v8h*>(&As[cur][(wm * 64 + s * 16 + rA) * 32 + kA]);
#pragma unroll
        for (int f = 0; f < 4; ++f)
            bf[f] = *reinterpret_cast<const v8h*>(&Bs[cur][(wn * 64 + f * 16 + rA) * 32 + kA]);
#pragma unroll
        for (int s = 0; s < 4; ++s)
#pragma unroll
            for (int f = 0; f < 4; ++f)
                acc[s][f] = __builtin_amdgcn_mfma_f32_16x16x32_f16(af[s], bf[f], acc[s][f], 0, 0, 0);
    }
    // fold bias into acc
#pragma unroll
    for (int f = 0; f < 4; ++f) {
        float bias = Ab[col0 + wn * 64 + f * 16 + (lane & 15)];
#pragma unroll
        for (int s = 0; s < 4; ++s)
#pragma unroll
            for (int r = 0; r < 4; ++r) acc[s][f][r] += bias;
    }
    // LDS-transposed coalesced epilogue: 4 rounds of 32 rows x 128 cols (16 KB)
    float* Ct = (float*)As;
#pragma unroll
    for (int s = 0; s < 4; ++s) {
        __syncthreads();
#pragma unroll
        for (int f = 0; f < 4; ++f) {
            int lc = wn * 64 + f * 16 + (lane & 15);
            int lr = wm * 16 + (lane >> 4) * 4;
#pragma unroll
            for (int r = 0; r < 4; ++r)
                Ct[(lr + r) * 128 + lc] = acc[s][f][r];
        }
        __syncthreads();
        int lr2 = tid >> 3;                       // 0..31
        int lc2 = (tid & 7) * 16;                 // 0,16,..,112
        int grow = row0 + (lr2 & 15) + (lr2 >> 4) * 64 + s * 16;
        float* dst = out + (size_t)grow * VOCAB + col0 + lc2;
        const float* srcl = &Ct[lr2 * 128 + lc2];
#pragma unroll
        for (int v = 0; v < 4; ++v)
            *reinterpret_cast<float4*>(dst + v * 4) =
                *reinterpret_cast<const float4*>(srcl + v * 4);
    }
}

// ---------------- host launch ----------------

extern "C" void kernel_launch(void* const* d_in, const int* in_sizes, int n_in,
                              void* d_out, int out_size, void* d_ws, size_t ws_size,
                              hipStream_t stream) {
    const int*   x        = (const int*)d_in[0];
    const float* W_in     = (const float*)d_in[1];
    const int*   rec_rows = (const int*)d_in[2];
    const int*   rec_cols = (const int*)d_in[3];
    const float* rec_vals = (const float*)d_in[4];
    const float* a        = (const float*)d_in[5];
    const float* B_w      = (const float*)d_in[6];
    const float* A_w      = (const float*)d_in[7];
    const float* A_b      = (const float*)d_in[8];
    float* out = (float*)d_out;

    char* w = (char*)d_ws;
    size_t off = 0;
    auto alloc = [&](size_t bytes) { void* p = w + off; off = (off + bytes + 255) & ~(size_t)255; return p; };

    unsigned short* Hb     = (unsigned short*)alloc((size_t)2048 * N_RES * 2);   // 16.8 MB
    unsigned short* Rbh    = (unsigned short*)alloc((size_t)2048 * R_OUT * 2);   // 2.1 MB
    unsigned short* Bwh    = (unsigned short*)alloc((size_t)R_OUT * N_RES * 2);  // 4.2 MB
    unsigned short* Awh    = (unsigned short*)alloc((size_t)VOCAB * R_OUT * 2);  // 32.8 MB
    unsigned*       csr    = (unsigned*)alloc((size_t)NNZ_CAP * 4);              // 655 KB
    int*            rowptr = (int*)alloc(4097 * 4);
    int*            cnt    = (int*)alloc(4096 * 4);
    int*            cursor = (int*)alloc(4096 * 4);
    unsigned long long* hx = (unsigned long long*)alloc(2 * TEAMS * 1024 * 8);   // 128 KB
    unsigned*       flags  = (unsigned*)alloc(FLAG_WORDS * 4);                   // 16 KB

    k_init<<<(INIT_WORDS + 255) / 256, 256, 0, stream>>>(csr, cnt, flags);

    k_hist<<<(NNZ + 255) / 256, 256, 0, stream>>>(rec_rows, cnt);
    k_scan<<<1, 1024, 0, stream>>>(cnt, rowptr, cursor);
    k_fill<<<(NNZ + 255) / 256, 256, 0, stream>>>(rec_rows, rec_cols, rec_vals, cursor, csr);

    k_cvt2<<<(NB8 + NA8 + 255) / 256, 256, 0, stream>>>(B_w, Bwh, A_w, Awh);

    k_steps<<<NWG, 256, 0, stream>>>(rowptr, csr, W_in, x, a, Hb, hx, flags);

    k_gemm1<<<dim3(R_OUT / 128, 2048 / 128), 256, 0, stream>>>(
        (const _Float16*)Hb, (const _Float16*)Bwh, Rbh);
    k_gemm2<<<dim3(VOCAB / 128, 2048 / 128), 256, 0, stream>>>(
        (const _Float16*)Rbh, (const _Float16*)Awh, A_b, out);
}